// Round 17
// baseline (360.687 us; speedup 1.0000x reference)
//
#include <hip/hip_runtime.h>
#include <math.h>

// Problem constants
#define BSZ 8
#define CW  32      // WIDTH (channels)
#define NN  256     // NX = NY
#define MM  16      // modes M1 = M2
#define NL  4
#define HID 128

typedef __attribute__((ext_vector_type(8))) short bf16x8;
typedef __attribute__((ext_vector_type(4))) short s16x4;
typedef __attribute__((ext_vector_type(4))) float f32x4;
typedef __attribute__((ext_vector_type(4))) unsigned int u32x4;

// ---------------------------------------------------------------------------
// Fast GELU via A&S 7.1.27, 1/sqrt2 folded into coefficients.
// gelu(v) = relu(v) - 0.5|v| * P(|v|)^-4.  One transcendental (rcp).
// ---------------------------------------------------------------------------
static __device__ __forceinline__ float gelu_f(float v) {
    float av = fabsf(v);
    float P  = fmaf(fmaf(fmaf(fmaf(0.01952700f, av, 0.00034365f), av, 0.11519450f),
                         av, 0.19685434f), av, 1.0f);
    float r  = __builtin_amdgcn_rcpf(P);
    float r2 = r * r;
    float r4 = r2 * r2;
    return fmaf(-0.5f * av, r4, fmaxf(v, 0.0f));
}

// fp32 -> (bf16 hi | bf16 lo) packed u32, truncation split (weights only)
static __device__ __forceinline__ unsigned pack_hl(float v) {
    unsigned b  = __float_as_uint(v);
    unsigned hi = b >> 16;
    float hif   = __uint_as_float(hi << 16);
    float lo    = v - hif;
    unsigned lou = __float_as_uint(lo) >> 16;
    return (hi << 16) | lou;
}

// fp32 -> bf16 round-to-nearest-even (activations)
static __device__ __forceinline__ short bf16_rne(float v) {
    unsigned u = __float_as_uint(v);
    u += 0x7fffu + ((u >> 16) & 1u);
    return (short)(u >> 16);
}

#define TWO_PI_OVER_N (6.28318530717958647692f / 256.0f)

// ---------------------------------------------------------------------------
// Prep (grid 32): ALL weight operands as separate hi/lo bf16-short planes
// in frag element order (zero-unpack loads).
// ---------------------------------------------------------------------------
__global__ void k_prep(const float* __restrict__ w1, const float* __restrict__ w2,
                       const float* __restrict__ pww,
                       short* __restrict__ wb1h, short* __restrict__ wb1l,
                       short* __restrict__ wb2h, short* __restrict__ wb2l,
                       short* __restrict__ wpwh, short* __restrict__ wpwl,
                       short* __restrict__ wifh, short* __restrict__ wifl,
                       short* __restrict__ wfyh, short* __restrict__ wfyl) {
    int t0 = blockIdx.x * 256 + threadIdx.x;
    for (int idx = t0; idx < 3 * 2 * 16 * 32; idx += 8192) {
        int k = idx & 31, n16 = (idx >> 5) & 15, nb = (idx >> 9) & 1, d = idx >> 10;
        unsigned p = pack_hl(w1[d * 1024 + k * 32 + nb * 16 + n16]);
        wb1h[idx] = (short)(p >> 16);
        wb1l[idx] = (short)(p & 0xffffu);
    }
    for (int idx = t0; idx < 3 * 8 * 16 * 32; idx += 8192) {
        int k = idx & 31, n16 = (idx >> 5) & 15, blk = (idx >> 9) & 7, d = idx >> 12;
        unsigned p = pack_hl(w2[d * 4096 + k * 128 + blk * 16 + n16]);
        wb2h[idx] = (short)(p >> 16);
        wb2l[idx] = (short)(p & 0xffffu);
    }
    for (int idx = t0; idx < NL * 1024; idx += 8192) {
        unsigned p = pack_hl(pww[idx]);
        wpwh[idx] = (short)(p >> 16);
        wpwl[idx] = (short)(p & 0xffffu);
    }
    for (int idx = t0; idx < 16 * 64 * 8; idx += 8192) {
        int j = idx & 7, l = (idx >> 3) & 63, ntg = idx >> 9;
        int k = ((l >> 4) << 3) + j, y = (ntg << 4) + (l & 15);
        int ky = k >> 1, p = k & 1;
        float v;
        if (k == 0)      v = 1.0f / 256.0f;
        else if (k == 1) v = 0.0f;
        else {
            float ang = TWO_PI_OVER_N * (float)((ky * y) & 255);
            v = p ? (-2.0f / 256.0f) * sinf(ang) : (2.0f / 256.0f) * cosf(ang);
        }
        unsigned pb = pack_hl(v);
        wifh[idx] = (short)(pb >> 16);
        wifl[idx] = (short)(pb & 0xffffu);
    }
    for (int idx = t0; idx < 16 * 64 * 8; idx += 8192) {
        int j = idx & 7, l = (idx >> 3) & 63, f = idx >> 9;
        int nt = f & 1, kstep = f >> 1;
        int y  = (kstep >> 1) * 64 + (kstep & 1) * 32 + ((l >> 4) << 3) + j;
        int kc = nt * 16 + (l & 15);
        int ky = kc >> 1, p = kc & 1;
        float ang = TWO_PI_OVER_N * (float)((ky * y) & 255);
        float v = p ? -sinf(ang) : cosf(ang);
        unsigned pb = pack_hl(v);
        wfyh[idx] = (short)(pb >> 16);
        wfyl[idx] = (short)(pb & 0xffffu);
    }
}

// ---------------------------------------------------------------------------
// Shared tail: forward y-DFT GEMM via MFMA from a SINGLE per-wave LDS
// bf16 h-tile (activations bf16; twiddles hi/lo -> 2 pass).
// ---------------------------------------------------------------------------
static __device__ __forceinline__ void dft_y_mfma(
        const short* __restrict__ hlsh, float* __restrict__ red,
        const short* __restrict__ wfyh, const short* __restrict__ wfyl,
        float* __restrict__ gy, int b, int x, int wv, int lk, int l15, int tid) {
    f32x4 acc2[2][2];
#pragma unroll
    for (int mt = 0; mt < 2; ++mt)
#pragma unroll
        for (int nt = 0; nt < 2; ++nt) acc2[mt][nt] = (f32x4){0.f, 0.f, 0.f, 0.f};
#pragma unroll
    for (int kk = 0; kk < 2; ++kk) {
        bf16x8 ahh[2];
#pragma unroll
        for (int mt = 0; mt < 2; ++mt) {
            int c  = mt * 16 + l15;
            int yl = (kk * 32 + lk * 8) ^ ((c & 7) << 3);
            ahh[mt] = *(const bf16x8*)&hlsh[c * 64 + yl];
        }
#pragma unroll
        for (int nt = 0; nt < 2; ++nt) {
            int fb = (((wv * 2 + kk) * 2 + nt) * 64 + (tid & 63)) * 8;
            bf16x8 bh = *(const bf16x8*)&wfyh[fb];
            bf16x8 bl = *(const bf16x8*)&wfyl[fb];
#pragma unroll
            for (int mt = 0; mt < 2; ++mt) {
                f32x4 a = acc2[mt][nt];
                a = __builtin_amdgcn_mfma_f32_16x16x32_bf16(ahh[mt], bl, a, 0, 0, 0);
                a = __builtin_amdgcn_mfma_f32_16x16x32_bf16(ahh[mt], bh, a, 0, 0, 0);
                acc2[mt][nt] = a;
            }
        }
    }
#pragma unroll
    for (int mt = 0; mt < 2; ++mt)
#pragma unroll
        for (int nt = 0; nt < 2; ++nt)
#pragma unroll
            for (int r = 0; r < 4; ++r)
                red[(wv * 32 + mt * 16 + lk * 4 + r) * 33 + nt * 16 + l15] =
                    acc2[mt][nt][r];
    __syncthreads();
#pragma unroll
    for (int e = 0; e < 4; ++e) {
        int idx = e * 256 + tid;
        int c = idx >> 5, kc = idx & 31;
        float v = red[(c) * 33 + kc] + red[(32 + c) * 33 + kc]
                + red[(64 + c) * 33 + kc] + red[(96 + c) * 33 + kc];
        gy[((size_t)(b * 32 + c)) * 8192 + x * 32 + kc] = v;
    }
}

// ---------------------------------------------------------------------------
// Fused lifting + forward y-DFT.  Block (b,x), thread = y.
// ---------------------------------------------------------------------------
__global__ void __launch_bounds__(256) k_lift_fy(
        const float* __restrict__ bc, const float* __restrict__ xg,
        const float* __restrict__ yg, const float* __restrict__ w,
        const float* __restrict__ bias, float* __restrict__ h,
        const short* __restrict__ wfyh, const short* __restrict__ wfyl,
        float* __restrict__ gy) {
    __shared__ short hlsh[4][2048];
    __shared__ float red[4224];
    int tid = threadIdx.x;
    int wv = tid >> 6, lk = (tid >> 4) & 3, l15 = tid & 15;
    int bx = blockIdx.x, b = bx >> 8, x = bx & 255;
    int y = tid;
    float i0 = bc[b * 3 + 0], i1 = bc[b * 3 + 1], i2 = bc[b * 3 + 2];
    float i3 = xg[b * 65536 + x * 256 + y];
    float i4 = yg[b * 65536 + x * 256 + y];
    size_t hb = (((size_t)b * 32) << 16) + x * 256 + y;
#pragma unroll
    for (int c = 0; c < 32; ++c) {
        float v = i0 * w[c] + i1 * w[CW + c] + i2 * w[2 * CW + c]
                + i3 * w[3 * CW + c] + i4 * w[4 * CW + c] + bias[c];
        h[hb + ((size_t)c << 16)] = v;
        int sl = (y & 63) ^ ((c & 7) << 3);
        hlsh[wv][c * 64 + sl] = bf16_rne(v);
    }
    dft_y_mfma(&hlsh[wv][0], red, wfyh, wfyl, gy, b, x, wv, lk, l15, tid);
}

// ---------------------------------------------------------------------------
// Forward DFT along x, 1024 threads (split-K + LDS reduce) — unchanged
// ---------------------------------------------------------------------------
__global__ void __launch_bounds__(1024) k_fwd_x(const float* __restrict__ gy,
                                                float* __restrict__ Xf) {
    __shared__ float g[8192];           // (x, c) 32 KB
    __shared__ float part[4][256][2];   // 8 KB
    __shared__ float ct[256], st[256];
    int tid = threadIdx.x;
    if (tid < 256) {
        float ang = (float)tid * TWO_PI_OVER_N;
        ct[tid] = cosf(ang);
        st[tid] = sinf(ang);
    }
    size_t base = (size_t)blockIdx.x * 8192;
#pragma unroll
    for (int j = 0; j < 8; ++j) g[j * 1024 + tid] = gy[base + j * 1024 + tid];
    __syncthreads();

    int t = tid & 255, xq = tid >> 8;
    int kx = t >> 4, ky = t & 15;
    float ar = 0.f, ai = 0.f;
    int x0 = xq * 64;
    int idx = (kx * x0) & 255;
#pragma unroll 4
    for (int x = x0; x < x0 + 64; ++x) {
        float c = ct[idx], s = st[idx];
        float gr = g[x * 32 + ky * 2], gi = g[x * 32 + ky * 2 + 1];
        ar += gr * c + gi * s;          // e^{-i}
        ai += gi * c - gr * s;
        idx = (idx + kx) & 255;
    }
    part[xq][t][0] = ar;
    part[xq][t][1] = ai;
    __syncthreads();
    if (tid < 256) {
        float a0 = part[0][tid][0] + part[1][tid][0] + part[2][tid][0] + part[3][tid][0];
        float a1 = part[0][tid][1] + part[1][tid][1] + part[2][tid][1] + part[3][tid][1];
        Xf[((size_t)blockIdx.x * 256 + tid) * 2 + 0] = a0 * (1.0f / 256.0f);
        Xf[((size_t)blockIdx.x * 256 + tid) * 2 + 1] = a1 * (1.0f / 256.0f);
    }
}

// ---------------------------------------------------------------------------
// Fused mode-mix + inverse x-DFT, 1024 threads. Block = (b,o) — unchanged
// ---------------------------------------------------------------------------
__global__ void __launch_bounds__(1024) k_spec(const float* __restrict__ Xf,
                                               const float* __restrict__ wr,
                                               const float* __restrict__ wi,
                                               float* __restrict__ gi) {
    __shared__ float tl[512];
    __shared__ float pp[4][256][2];
    __shared__ float ct[256], st[256];
    int tid = threadIdx.x;
    if (tid < 256) {
        float ang = (float)tid * TWO_PI_OVER_N;
        ct[tid] = cosf(ang);
        st[tid] = sinf(ang);
    }
    int b = blockIdx.x >> 5, o = blockIdx.x & 31;
    int t = tid & 255, ig = tid >> 8;

    float tr = 0.f, ti = 0.f;
    const float2* xp = (const float2*)Xf + (size_t)b * 8192 + t;
    const float* wrp = wr + (size_t)o * 256 + t;
    const float* wip = wi + (size_t)o * 256 + t;
#pragma unroll
    for (int i = ig * 8; i < ig * 8 + 8; ++i) {
        float2 xv = xp[i * 256];
        float wrv = wrp[(size_t)i * 8192];
        float wiv = wip[(size_t)i * 8192];
        tr += xv.x * wrv - xv.y * wiv;
        ti += xv.x * wiv + xv.y * wrv;
    }
    pp[ig][t][0] = tr;
    pp[ig][t][1] = ti;
    __syncthreads();
    if (tid < 256) {
        tl[tid * 2 + 0] = pp[0][tid][0] + pp[1][tid][0] + pp[2][tid][0] + pp[3][tid][0];
        tl[tid * 2 + 1] = pp[0][tid][1] + pp[1][tid][1] + pp[2][tid][1] + pp[3][tid][1];
    }
    __syncthreads();

    int x = t, kg = ig;
    float gre[4], gim[4];
#pragma unroll
    for (int k = 0; k < 4; ++k) { gre[k] = 0.f; gim[k] = 0.f; }
#pragma unroll 4
    for (int kx = 0; kx < 16; ++kx) {
        int idx = (kx * x) & 255;
        float c = ct[idx], s = st[idx];
#pragma unroll
        for (int k = 0; k < 4; ++k) {
            int ky = kg * 4 + k;
            float t2r = tl[(kx * 16 + ky) * 2 + 0];
            float t2i = tl[(kx * 16 + ky) * 2 + 1];
            gre[k] += t2r * c - t2i * s;   // e^{+i}
            gim[k] += t2i * c + t2r * s;
        }
    }
    size_t ob = (((size_t)b * 256 + x) * 32 + o) * 32;
#pragma unroll
    for (int k = 0; k < 4; ++k) {
        gi[ob + (kg * 4 + k) * 2 + 0] = gre[k];
        gi[ob + (kg * 4 + k) * 2 + 1] = gim[k];
    }
}

// ---------------------------------------------------------------------------
// MFMA k_update (round 16 version, passing) — activations bf16, weights hi/lo
// ---------------------------------------------------------------------------
__global__ void __launch_bounds__(256) k_update(float* __restrict__ h,
        const float* __restrict__ gi,
        const short* __restrict__ wpwh, const short* __restrict__ wpwl,
        const float* __restrict__ pwb,
        const short* __restrict__ wifh, const short* __restrict__ wifl,
        const short* __restrict__ wfyh, const short* __restrict__ wfyl,
        float* __restrict__ gy, int do_fy) {
    __shared__ short hlsh[4][2048];
    __shared__ float red[4224];
    int tid = threadIdx.x;
    int wv = tid >> 6, l = tid & 63;
    int l15 = l & 15, lk = l >> 4;
    int bx = blockIdx.x, b = bx >> 8, x = bx & 255;
    float* hx = h + (((size_t)b * 32) << 16) + x * 256;   // + c*65536 + y

    bf16x8 gt[2], wh[2], wl[2];
    const float* gp = gi + (size_t)bx * 1024;
#pragma unroll
    for (int mt = 0; mt < 2; ++mt) {
        const float* ap = gp + (mt * 16 + l15) * 32 + lk * 8;
        float4 a0 = *(const float4*)ap;
        float4 a1 = *(const float4*)(ap + 4);
        gt[mt][0] = bf16_rne(a0.x); gt[mt][1] = bf16_rne(a0.y);
        gt[mt][2] = bf16_rne(a0.z); gt[mt][3] = bf16_rne(a0.w);
        gt[mt][4] = bf16_rne(a1.x); gt[mt][5] = bf16_rne(a1.y);
        gt[mt][6] = bf16_rne(a1.z); gt[mt][7] = bf16_rne(a1.w);
        int wbase = (mt * 16 + l15) * 32 + lk * 8;
        wh[mt] = *(const bf16x8*)(wpwh + wbase);
        wl[mt] = *(const bf16x8*)(wpwl + wbase);
    }

    f32x4 acc[2][4];
#pragma unroll
    for (int nt = 0; nt < 4; ++nt) {
        int y = wv * 64 + nt * 16 + l15;
        int ntg = wv * 4 + nt;
        int qb = ntg * 512 + l * 8;
        bf16x8 wih = *(const bf16x8*)(wifh + qb);
        bf16x8 wil = *(const bf16x8*)(wifl + qb);
        bf16x8 hb;
#pragma unroll
        for (int j = 0; j < 8; ++j)
            hb[j] = bf16_rne(hx[((size_t)(lk * 8 + j) << 16) + y]);
#pragma unroll
        for (int mt = 0; mt < 2; ++mt) {
            f32x4 a = {0.f, 0.f, 0.f, 0.f};
            a = __builtin_amdgcn_mfma_f32_16x16x32_bf16(gt[mt], wil, a, 0, 0, 0);
            a = __builtin_amdgcn_mfma_f32_16x16x32_bf16(gt[mt], wih, a, 0, 0, 0);
            a = __builtin_amdgcn_mfma_f32_16x16x32_bf16(wl[mt], hb, a, 0, 0, 0);
            a = __builtin_amdgcn_mfma_f32_16x16x32_bf16(wh[mt], hb, a, 0, 0, 0);
            acc[mt][nt] = a;
        }
    }

    float hold[2][4][4];
#pragma unroll
    for (int mt = 0; mt < 2; ++mt)
#pragma unroll
        for (int nt = 0; nt < 4; ++nt) {
            int y = wv * 64 + nt * 16 + l15;
#pragma unroll
            for (int r = 0; r < 4; ++r)
                hold[mt][nt][r] = hx[((size_t)(mt * 16 + lk * 4 + r) << 16) + y];
        }
#pragma unroll
    for (int mt = 0; mt < 2; ++mt)
#pragma unroll
        for (int nt = 0; nt < 4; ++nt) {
            int y = wv * 64 + nt * 16 + l15;
#pragma unroll
            for (int r = 0; r < 4; ++r) {
                int o = mt * 16 + lk * 4 + r;
                float u = acc[mt][nt][r] + pwb[o];
                float hn = hold[mt][nt][r] + gelu_f(u);
                hx[((size_t)o << 16) + y] = hn;
                if (do_fy) {
                    int sl = (nt * 16 + l15) ^ ((o & 7) << 3);
                    hlsh[wv][o * 64 + sl] = bf16_rne(hn);
                }
            }
        }
    if (do_fy)
        dft_y_mfma(&hlsh[wv][0], red, wfyh, wfyl, gy, b, x, wv, lk, l15, tid);
}

// ---------------------------------------------------------------------------
// MFMA decoder, round 17: MT=2 grid 4096, single-bf16 activations, plus
// (a) hoisted d-invariant swizzled z1 write/read addressing:
//     write addr(mt,nb,r) = rowbase(mt) + r*32 + (s0 ^ (r<<2) ^ (nb<<4))
//     (shift distributes over XOR), (b) read bases rb[mt], q1 = q0 ^ 4,
// (c) fully-unrolled blk loop so all 16 w2 loads issue early.
// ---------------------------------------------------------------------------
__global__ void __launch_bounds__(256) k_decode(const float* __restrict__ h,
        const short* __restrict__ wb1h, const short* __restrict__ wb1l,
        const float* __restrict__ b1,
        const short* __restrict__ wb2h, const short* __restrict__ wb2l,
        const float* __restrict__ b2,
        const float* __restrict__ w3, const float* __restrict__ b3,
        float* __restrict__ out) {
    __shared__ short z1s[4][32][32];        // per-wave, swizzled, 8 KB
    int tid = threadIdx.x;
    int wv = tid >> 6, l = tid & 63;
    int l15 = l & 15, lk = l >> 4;
    int b = blockIdx.x >> 9;
    int pos0 = (blockIdx.x & 511) * 128;
    short* z1b = &z1s[wv][0][0];

    // d-invariant addressing (hoisted):
    // write: slot(nb,r) = (((l15>>2) ^ ((lk&1)<<2)) << 2 | (l15&3)) ^ (r<<2) ^ (nb<<4)
    int s0 = ((((l15 >> 2) ^ ((lk & 1) << 2)) << 2) | (l15 & 3));
    int wrow0 = lk * 4 * 32;                 // + mt*16*32 + r*32
    // read: rb(mt) = (mt*16+l15)*32 + (((2*lk)^(l15&7))<<2);  q1 = q0 ^ 4
    int rb0 = l15 * 32 + (((2 * lk) ^ (l15 & 7)) << 2);

    bf16x8 ah[2];
    const float* hb = h + (((size_t)b * 32) << 16) + pos0;
#pragma unroll
    for (int mt = 0; mt < 2; ++mt) {
        int p = wv * 32 + mt * 16 + l15;
#pragma unroll
        for (int j = 0; j < 8; ++j)
            ah[mt][j] = bf16_rne(hb[((size_t)(lk * 8 + j) << 16) + p]);
    }

    size_t gbase = (size_t)blockIdx.x * 128 + wv * 32;
    for (int d = 0; d < 3; ++d) {
        bf16x8 w1h[2], w1l[2];
        float bias1[2];
#pragma unroll
        for (int nb = 0; nb < 2; ++nb) {
            int base = ((d * 2 + nb) * 16 + l15) * 32 + lk * 8;
            w1h[nb] = *(const bf16x8*)(wb1h + base);
            w1l[nb] = *(const bf16x8*)(wb1l + base);
            bias1[nb] = b1[d * 32 + nb * 16 + l15];
        }
#pragma unroll
        for (int mt = 0; mt < 2; ++mt) {
#pragma unroll
            for (int nb = 0; nb < 2; ++nb) {
                f32x4 acc = {0.f, 0.f, 0.f, 0.f};
                acc = __builtin_amdgcn_mfma_f32_16x16x32_bf16(ah[mt], w1l[nb], acc, 0, 0, 0);
                acc = __builtin_amdgcn_mfma_f32_16x16x32_bf16(ah[mt], w1h[nb], acc, 0, 0, 0);
                int wbase = wrow0 + mt * 512;
#pragma unroll
                for (int r = 0; r < 4; ++r) {
                    float z = gelu_f(acc[r] + bias1[nb]);
                    z1b[wbase + r * 32 + (s0 ^ (r << 2) ^ (nb << 4))] = bf16_rne(z);
                }
            }
        }
        bf16x8 zah[2];
#pragma unroll
        for (int mt = 0; mt < 2; ++mt) {
            int rb = rb0 + mt * 512;
            s16x4 q0 = *(const s16x4*)&z1b[rb];
            s16x4 q1 = *(const s16x4*)&z1b[rb ^ 4];
#pragma unroll
            for (int j = 0; j < 4; ++j) {
                zah[mt][j]     = q0[j];
                zah[mt][4 + j] = q1[j];
            }
        }
        float p3[2][4];
#pragma unroll
        for (int mt = 0; mt < 2; ++mt)
#pragma unroll
            for (int r = 0; r < 4; ++r) p3[mt][r] = 0.f;
#pragma unroll
        for (int blk = 0; blk < 8; ++blk) {
            int base = ((d * 8 + blk) * 16 + l15) * 32 + lk * 8;
            bf16x8 bh  = *(const bf16x8*)(wb2h + base);
            bf16x8 bl2 = *(const bf16x8*)(wb2l + base);
            float bias2 = b2[d * 128 + blk * 16 + l15];
            float w3v   = w3[d * 128 + blk * 16 + l15];
#pragma unroll
            for (int mt = 0; mt < 2; ++mt) {
                f32x4 acc = {0.f, 0.f, 0.f, 0.f};
                acc = __builtin_amdgcn_mfma_f32_16x16x32_bf16(zah[mt], bl2, acc, 0, 0, 0);
                acc = __builtin_amdgcn_mfma_f32_16x16x32_bf16(zah[mt], bh, acc, 0, 0, 0);
#pragma unroll
                for (int r = 0; r < 4; ++r)
                    p3[mt][r] = fmaf(gelu_f(acc[r] + bias2), w3v, p3[mt][r]);
            }
        }
        float b3d = b3[d];
#pragma unroll
        for (int mt = 0; mt < 2; ++mt) {
#pragma unroll
            for (int r = 0; r < 4; ++r) {
                float v = p3[mt][r];
                v += __shfl_xor(v, 1, 64);
                v += __shfl_xor(v, 2, 64);
                v += __shfl_xor(v, 4, 64);
                v += __shfl_xor(v, 8, 64);
                if (l15 == r)
                    out[(gbase + mt * 16 + lk * 4 + r) * 3 + d] = v + b3d;
            }
        }
    }
}

// ---------------------------------------------------------------------------
// Workspace (floats). Total = 21,138,432 floats = 84,553,728 B — under
// round-1's proven-safe 84,934,656 B.
// ---------------------------------------------------------------------------
extern "C" void kernel_launch(void* const* d_in, const int* in_sizes, int n_in,
                              void* d_out, int out_size, void* d_ws, size_t ws_size,
                              hipStream_t stream) {
    const float* bc      = (const float*)d_in[0];
    const float* xg      = (const float*)d_in[1];
    const float* yg      = (const float*)d_in[2];
    const float* mlp1_w  = (const float*)d_in[3];
    const float* mlp1_b  = (const float*)d_in[4];
    const float* spec_wr = (const float*)d_in[5];
    const float* spec_wi = (const float*)d_in[6];
    const float* pw_w    = (const float*)d_in[7];
    const float* pw_b    = (const float*)d_in[8];
    const float* dec_w1  = (const float*)d_in[9];
    const float* dec_b1  = (const float*)d_in[10];
    const float* dec_w2  = (const float*)d_in[11];
    const float* dec_b2  = (const float*)d_in[12];
    const float* dec_w3  = (const float*)d_in[13];
    const float* dec_b3  = (const float*)d_in[14];
    float* out = (float*)d_out;

    float* h    = (float*)d_ws;               // 16,777,216 floats
    float* gi   = h + 16777216;               //  2,097,152
    float* gy   = gi + 2097152;               //  2,097,152
    float* Xf   = gy + 2097152;               //    131,072
    short* wb1h = (short*)(Xf + 131072);      //      3,072 shorts
    short* wb1l = wb1h + 3072;                //      3,072
    short* wb2h = wb1l + 3072;                //     12,288
    short* wb2l = wb2h + 12288;               //     12,288
    short* wpwh = wb2l + 12288;               //      4,096
    short* wpwl = wpwh + 4096;                //      4,096
    short* wifh = wpwl + 4096;                //      8,192
    short* wifl = wifh + 8192;                //      8,192
    short* wfyh = wifl + 8192;                //      8,192
    short* wfyl = wfyh + 8192;                //      8,192
    (void)ws_size; (void)n_in; (void)in_sizes; (void)out_size;

    k_prep<<<32, 256, 0, stream>>>(dec_w1, dec_w2, pw_w,
                                   wb1h, wb1l, wb2h, wb2l,
                                   wpwh, wpwl, wifh, wifl, wfyh, wfyl);
    k_lift_fy<<<2048, 256, 0, stream>>>(bc, xg, yg, mlp1_w, mlp1_b, h,
                                        wfyh, wfyl, gy);
    for (int l = 0; l < NL; ++l) {
        k_fwd_x<<<256, 1024, 0, stream>>>(gy, Xf);
        k_spec<<<256, 1024, 0, stream>>>(Xf, spec_wr + (size_t)l * 262144,
                                         spec_wi + (size_t)l * 262144, gi);
        k_update<<<2048, 256, 0, stream>>>(h, gi, wpwh + l * 1024, wpwl + l * 1024,
                                           pw_b + l * 32, wifh, wifl,
                                           wfyh, wfyl, gy, (l < NL - 1) ? 1 : 0);
    }
    k_decode<<<4096, 256, 0, stream>>>(h, wb1h, wb1l, dec_b1, wb2h, wb2l, dec_b2,
                                       dec_w3, dec_b3, out);
}

// Round 18
// 326.128 us; speedup vs baseline: 1.1060x; 1.1060x over previous
//
#include <hip/hip_runtime.h>
#include <math.h>

// Problem constants
#define BSZ 8
#define CW  32      // WIDTH (channels)
#define NN  256     // NX = NY
#define MM  16      // modes M1 = M2
#define NL  4
#define HID 128

typedef __attribute__((ext_vector_type(8))) short bf16x8;
typedef __attribute__((ext_vector_type(4))) short s16x4;
typedef __attribute__((ext_vector_type(4))) float f32x4;
typedef __attribute__((ext_vector_type(4))) unsigned int u32x4;

// ---------------------------------------------------------------------------
// Fast GELU via A&S 7.1.27, 1/sqrt2 folded into coefficients.
// gelu(v) = relu(v) - 0.5|v| * P(|v|)^-4.  One transcendental (rcp).
// ---------------------------------------------------------------------------
static __device__ __forceinline__ float gelu_f(float v) {
    float av = fabsf(v);
    float P  = fmaf(fmaf(fmaf(fmaf(0.01952700f, av, 0.00034365f), av, 0.11519450f),
                         av, 0.19685434f), av, 1.0f);
    float r  = __builtin_amdgcn_rcpf(P);
    float r2 = r * r;
    float r4 = r2 * r2;
    return fmaf(-0.5f * av, r4, fmaxf(v, 0.0f));
}

// fp32 -> (bf16 hi | bf16 lo) packed u32, truncation split (weights only)
static __device__ __forceinline__ unsigned pack_hl(float v) {
    unsigned b  = __float_as_uint(v);
    unsigned hi = b >> 16;
    float hif   = __uint_as_float(hi << 16);
    float lo    = v - hif;
    unsigned lou = __float_as_uint(lo) >> 16;
    return (hi << 16) | lou;
}

// fp32 -> bf16 round-to-nearest-even (activations)
static __device__ __forceinline__ short bf16_rne(float v) {
    unsigned u = __float_as_uint(v);
    u += 0x7fffu + ((u >> 16) & 1u);
    return (short)(u >> 16);
}

#define TWO_PI_OVER_N (6.28318530717958647692f / 256.0f)

// ---------------------------------------------------------------------------
// Prep (grid 32): ALL weight operands as separate hi/lo bf16-short planes
// in frag element order (zero-unpack loads). Weights keep full precision
// via hi/lo; runtime activations are single bf16.
// ---------------------------------------------------------------------------
__global__ void k_prep(const float* __restrict__ w1, const float* __restrict__ w2,
                       const float* __restrict__ pww,
                       short* __restrict__ wb1h, short* __restrict__ wb1l,
                       short* __restrict__ wb2h, short* __restrict__ wb2l,
                       short* __restrict__ wpwh, short* __restrict__ wpwl,
                       short* __restrict__ wifh, short* __restrict__ wifl,
                       short* __restrict__ wfyh, short* __restrict__ wfyl) {
    int t0 = blockIdx.x * 256 + threadIdx.x;
    for (int idx = t0; idx < 3 * 2 * 16 * 32; idx += 8192) {
        int k = idx & 31, n16 = (idx >> 5) & 15, nb = (idx >> 9) & 1, d = idx >> 10;
        unsigned p = pack_hl(w1[d * 1024 + k * 32 + nb * 16 + n16]);
        wb1h[idx] = (short)(p >> 16);
        wb1l[idx] = (short)(p & 0xffffu);
    }
    for (int idx = t0; idx < 3 * 8 * 16 * 32; idx += 8192) {
        int k = idx & 31, n16 = (idx >> 5) & 15, blk = (idx >> 9) & 7, d = idx >> 12;
        unsigned p = pack_hl(w2[d * 4096 + k * 128 + blk * 16 + n16]);
        wb2h[idx] = (short)(p >> 16);
        wb2l[idx] = (short)(p & 0xffffu);
    }
    for (int idx = t0; idx < NL * 1024; idx += 8192) {
        unsigned p = pack_hl(pww[idx]);
        wpwh[idx] = (short)(p >> 16);
        wpwl[idx] = (short)(p & 0xffffu);
    }
    for (int idx = t0; idx < 16 * 64 * 8; idx += 8192) {
        int j = idx & 7, l = (idx >> 3) & 63, ntg = idx >> 9;
        int k = ((l >> 4) << 3) + j, y = (ntg << 4) + (l & 15);
        int ky = k >> 1, p = k & 1;
        float v;
        if (k == 0)      v = 1.0f / 256.0f;
        else if (k == 1) v = 0.0f;
        else {
            float ang = TWO_PI_OVER_N * (float)((ky * y) & 255);
            v = p ? (-2.0f / 256.0f) * sinf(ang) : (2.0f / 256.0f) * cosf(ang);
        }
        unsigned pb = pack_hl(v);
        wifh[idx] = (short)(pb >> 16);
        wifl[idx] = (short)(pb & 0xffffu);
    }
    for (int idx = t0; idx < 16 * 64 * 8; idx += 8192) {
        int j = idx & 7, l = (idx >> 3) & 63, f = idx >> 9;
        int nt = f & 1, kstep = f >> 1;
        int y  = (kstep >> 1) * 64 + (kstep & 1) * 32 + ((l >> 4) << 3) + j;
        int kc = nt * 16 + (l & 15);
        int ky = kc >> 1, p = kc & 1;
        float ang = TWO_PI_OVER_N * (float)((ky * y) & 255);
        float v = p ? -sinf(ang) : cosf(ang);
        unsigned pb = pack_hl(v);
        wfyh[idx] = (short)(pb >> 16);
        wfyl[idx] = (short)(pb & 0xffffu);
    }
}

// ---------------------------------------------------------------------------
// Shared tail: forward y-DFT GEMM via MFMA from a SINGLE per-wave LDS
// bf16 h-tile (activations single-precision-bf16; twiddles hi/lo -> 2 pass).
// ---------------------------------------------------------------------------
static __device__ __forceinline__ void dft_y_mfma(
        const short* __restrict__ hlsh, float* __restrict__ red,
        const short* __restrict__ wfyh, const short* __restrict__ wfyl,
        float* __restrict__ gy, int b, int x, int wv, int lk, int l15, int tid) {
    f32x4 acc2[2][2];
#pragma unroll
    for (int mt = 0; mt < 2; ++mt)
#pragma unroll
        for (int nt = 0; nt < 2; ++nt) acc2[mt][nt] = (f32x4){0.f, 0.f, 0.f, 0.f};
#pragma unroll
    for (int kk = 0; kk < 2; ++kk) {
        bf16x8 ahh[2];
#pragma unroll
        for (int mt = 0; mt < 2; ++mt) {
            int c  = mt * 16 + l15;
            int yl = (kk * 32 + lk * 8) ^ ((c & 7) << 3);
            ahh[mt] = *(const bf16x8*)&hlsh[c * 64 + yl];
        }
#pragma unroll
        for (int nt = 0; nt < 2; ++nt) {
            int fb = (((wv * 2 + kk) * 2 + nt) * 64 + (tid & 63)) * 8;
            bf16x8 bh = *(const bf16x8*)&wfyh[fb];
            bf16x8 bl = *(const bf16x8*)&wfyl[fb];
#pragma unroll
            for (int mt = 0; mt < 2; ++mt) {
                f32x4 a = acc2[mt][nt];
                a = __builtin_amdgcn_mfma_f32_16x16x32_bf16(ahh[mt], bl, a, 0, 0, 0);
                a = __builtin_amdgcn_mfma_f32_16x16x32_bf16(ahh[mt], bh, a, 0, 0, 0);
                acc2[mt][nt] = a;
            }
        }
    }
#pragma unroll
    for (int mt = 0; mt < 2; ++mt)
#pragma unroll
        for (int nt = 0; nt < 2; ++nt)
#pragma unroll
            for (int r = 0; r < 4; ++r)
                red[(wv * 32 + mt * 16 + lk * 4 + r) * 33 + nt * 16 + l15] =
                    acc2[mt][nt][r];
    __syncthreads();
#pragma unroll
    for (int e = 0; e < 4; ++e) {
        int idx = e * 256 + tid;
        int c = idx >> 5, kc = idx & 31;
        float v = red[(c) * 33 + kc] + red[(32 + c) * 33 + kc]
                + red[(64 + c) * 33 + kc] + red[(96 + c) * 33 + kc];
        gy[((size_t)(b * 32 + c)) * 8192 + x * 32 + kc] = v;
    }
}

// ---------------------------------------------------------------------------
// Fused lifting + forward y-DFT.  Block (b,x), thread = y.
// ---------------------------------------------------------------------------
__global__ void __launch_bounds__(256) k_lift_fy(
        const float* __restrict__ bc, const float* __restrict__ xg,
        const float* __restrict__ yg, const float* __restrict__ w,
        const float* __restrict__ bias, float* __restrict__ h,
        const short* __restrict__ wfyh, const short* __restrict__ wfyl,
        float* __restrict__ gy) {
    __shared__ short hlsh[4][2048];
    __shared__ float red[4224];
    int tid = threadIdx.x;
    int wv = tid >> 6, lk = (tid >> 4) & 3, l15 = tid & 15;
    int bx = blockIdx.x, b = bx >> 8, x = bx & 255;
    int y = tid;
    float i0 = bc[b * 3 + 0], i1 = bc[b * 3 + 1], i2 = bc[b * 3 + 2];
    float i3 = xg[b * 65536 + x * 256 + y];
    float i4 = yg[b * 65536 + x * 256 + y];
    size_t hb = (((size_t)b * 32) << 16) + x * 256 + y;
#pragma unroll
    for (int c = 0; c < 32; ++c) {
        float v = i0 * w[c] + i1 * w[CW + c] + i2 * w[2 * CW + c]
                + i3 * w[3 * CW + c] + i4 * w[4 * CW + c] + bias[c];
        h[hb + ((size_t)c << 16)] = v;
        int sl = (y & 63) ^ ((c & 7) << 3);
        hlsh[wv][c * 64 + sl] = bf16_rne(v);
    }
    dft_y_mfma(&hlsh[wv][0], red, wfyh, wfyl, gy, b, x, wv, lk, l15, tid);
}

// ---------------------------------------------------------------------------
// Forward DFT along x, 1024 threads (split-K + LDS reduce)
// ---------------------------------------------------------------------------
__global__ void __launch_bounds__(1024) k_fwd_x(const float* __restrict__ gy,
                                                float* __restrict__ Xf) {
    __shared__ float g[8192];           // (x, c) 32 KB
    __shared__ float part[4][256][2];   // 8 KB
    __shared__ float ct[256], st[256];
    int tid = threadIdx.x;
    if (tid < 256) {
        float ang = (float)tid * TWO_PI_OVER_N;
        ct[tid] = cosf(ang);
        st[tid] = sinf(ang);
    }
    size_t base = (size_t)blockIdx.x * 8192;
#pragma unroll
    for (int j = 0; j < 8; ++j) g[j * 1024 + tid] = gy[base + j * 1024 + tid];
    __syncthreads();

    int t = tid & 255, xq = tid >> 8;
    int kx = t >> 4, ky = t & 15;
    float ar = 0.f, ai = 0.f;
    int x0 = xq * 64;
    int idx = (kx * x0) & 255;
#pragma unroll 4
    for (int x = x0; x < x0 + 64; ++x) {
        float c = ct[idx], s = st[idx];
        float gr = g[x * 32 + ky * 2], gi = g[x * 32 + ky * 2 + 1];
        ar += gr * c + gi * s;          // e^{-i}
        ai += gi * c - gr * s;
        idx = (idx + kx) & 255;
    }
    part[xq][t][0] = ar;
    part[xq][t][1] = ai;
    __syncthreads();
    if (tid < 256) {
        float a0 = part[0][tid][0] + part[1][tid][0] + part[2][tid][0] + part[3][tid][0];
        float a1 = part[0][tid][1] + part[1][tid][1] + part[2][tid][1] + part[3][tid][1];
        Xf[((size_t)blockIdx.x * 256 + tid) * 2 + 0] = a0 * (1.0f / 256.0f);
        Xf[((size_t)blockIdx.x * 256 + tid) * 2 + 1] = a1 * (1.0f / 256.0f);
    }
}

// ---------------------------------------------------------------------------
// Fused mode-mix + inverse x-DFT, 1024 threads. Block = (b,o)
// ---------------------------------------------------------------------------
__global__ void __launch_bounds__(1024) k_spec(const float* __restrict__ Xf,
                                               const float* __restrict__ wr,
                                               const float* __restrict__ wi,
                                               float* __restrict__ gi) {
    __shared__ float tl[512];
    __shared__ float pp[4][256][2];
    __shared__ float ct[256], st[256];
    int tid = threadIdx.x;
    if (tid < 256) {
        float ang = (float)tid * TWO_PI_OVER_N;
        ct[tid] = cosf(ang);
        st[tid] = sinf(ang);
    }
    int b = blockIdx.x >> 5, o = blockIdx.x & 31;
    int t = tid & 255, ig = tid >> 8;

    float tr = 0.f, ti = 0.f;
    const float2* xp = (const float2*)Xf + (size_t)b * 8192 + t;
    const float* wrp = wr + (size_t)o * 256 + t;
    const float* wip = wi + (size_t)o * 256 + t;
#pragma unroll
    for (int i = ig * 8; i < ig * 8 + 8; ++i) {
        float2 xv = xp[i * 256];
        float wrv = wrp[(size_t)i * 8192];
        float wiv = wip[(size_t)i * 8192];
        tr += xv.x * wrv - xv.y * wiv;
        ti += xv.x * wiv + xv.y * wrv;
    }
    pp[ig][t][0] = tr;
    pp[ig][t][1] = ti;
    __syncthreads();
    if (tid < 256) {
        tl[tid * 2 + 0] = pp[0][tid][0] + pp[1][tid][0] + pp[2][tid][0] + pp[3][tid][0];
        tl[tid * 2 + 1] = pp[0][tid][1] + pp[1][tid][1] + pp[2][tid][1] + pp[3][tid][1];
    }
    __syncthreads();

    int x = t, kg = ig;
    float gre[4], gim[4];
#pragma unroll
    for (int k = 0; k < 4; ++k) { gre[k] = 0.f; gim[k] = 0.f; }
#pragma unroll 4
    for (int kx = 0; kx < 16; ++kx) {
        int idx = (kx * x) & 255;
        float c = ct[idx], s = st[idx];
#pragma unroll
        for (int k = 0; k < 4; ++k) {
            int ky = kg * 4 + k;
            float t2r = tl[(kx * 16 + ky) * 2 + 0];
            float t2i = tl[(kx * 16 + ky) * 2 + 1];
            gre[k] += t2r * c - t2i * s;   // e^{+i}
            gim[k] += t2i * c + t2r * s;
        }
    }
    size_t ob = (((size_t)b * 256 + x) * 32 + o) * 32;
#pragma unroll
    for (int k = 0; k < 4; ++k) {
        gi[ob + (kg * 4 + k) * 2 + 0] = gre[k];
        gi[ob + (kg * 4 + k) * 2 + 1] = gim[k];
    }
}

// ---------------------------------------------------------------------------
// MFMA k_update: activations single-bf16, weights hi/lo prepacked.
// Per (mt,nt): 4 MFMA. Single hlsh plane. + fused forward y-DFT (do_fy).
// ---------------------------------------------------------------------------
__global__ void __launch_bounds__(256) k_update(float* __restrict__ h,
        const float* __restrict__ gi,
        const short* __restrict__ wpwh, const short* __restrict__ wpwl,
        const float* __restrict__ pwb,
        const short* __restrict__ wifh, const short* __restrict__ wifl,
        const short* __restrict__ wfyh, const short* __restrict__ wfyl,
        float* __restrict__ gy, int do_fy) {
    __shared__ short hlsh[4][2048];
    __shared__ float red[4224];
    int tid = threadIdx.x;
    int wv = tid >> 6, l = tid & 63;
    int l15 = l & 15, lk = l >> 4;
    int bx = blockIdx.x, b = bx >> 8, x = bx & 255;
    float* hx = h + (((size_t)b * 32) << 16) + x * 256;   // + c*65536 + y

    bf16x8 gt[2], wh[2], wl[2];
    const float* gp = gi + (size_t)bx * 1024;
#pragma unroll
    for (int mt = 0; mt < 2; ++mt) {
        const float* ap = gp + (mt * 16 + l15) * 32 + lk * 8;
        float4 a0 = *(const float4*)ap;
        float4 a1 = *(const float4*)(ap + 4);
        gt[mt][0] = bf16_rne(a0.x); gt[mt][1] = bf16_rne(a0.y);
        gt[mt][2] = bf16_rne(a0.z); gt[mt][3] = bf16_rne(a0.w);
        gt[mt][4] = bf16_rne(a1.x); gt[mt][5] = bf16_rne(a1.y);
        gt[mt][6] = bf16_rne(a1.z); gt[mt][7] = bf16_rne(a1.w);
        int wbase = (mt * 16 + l15) * 32 + lk * 8;
        wh[mt] = *(const bf16x8*)(wpwh + wbase);
        wl[mt] = *(const bf16x8*)(wpwl + wbase);
    }

    f32x4 acc[2][4];
#pragma unroll
    for (int nt = 0; nt < 4; ++nt) {
        int y = wv * 64 + nt * 16 + l15;
        int ntg = wv * 4 + nt;
        int qb = ntg * 512 + l * 8;
        bf16x8 wih = *(const bf16x8*)(wifh + qb);
        bf16x8 wil = *(const bf16x8*)(wifl + qb);
        bf16x8 hb;
#pragma unroll
        for (int j = 0; j < 8; ++j)
            hb[j] = bf16_rne(hx[((size_t)(lk * 8 + j) << 16) + y]);
#pragma unroll
        for (int mt = 0; mt < 2; ++mt) {
            f32x4 a = {0.f, 0.f, 0.f, 0.f};
            a = __builtin_amdgcn_mfma_f32_16x16x32_bf16(gt[mt], wil, a, 0, 0, 0);
            a = __builtin_amdgcn_mfma_f32_16x16x32_bf16(gt[mt], wih, a, 0, 0, 0);
            a = __builtin_amdgcn_mfma_f32_16x16x32_bf16(wl[mt], hb, a, 0, 0, 0);
            a = __builtin_amdgcn_mfma_f32_16x16x32_bf16(wh[mt], hb, a, 0, 0, 0);
            acc[mt][nt] = a;
        }
    }

    float hold[2][4][4];
#pragma unroll
    for (int mt = 0; mt < 2; ++mt)
#pragma unroll
        for (int nt = 0; nt < 4; ++nt) {
            int y = wv * 64 + nt * 16 + l15;
#pragma unroll
            for (int r = 0; r < 4; ++r)
                hold[mt][nt][r] = hx[((size_t)(mt * 16 + lk * 4 + r) << 16) + y];
        }
#pragma unroll
    for (int mt = 0; mt < 2; ++mt)
#pragma unroll
        for (int nt = 0; nt < 4; ++nt) {
            int y = wv * 64 + nt * 16 + l15;
#pragma unroll
            for (int r = 0; r < 4; ++r) {
                int o = mt * 16 + lk * 4 + r;
                float u = acc[mt][nt][r] + pwb[o];
                float hn = hold[mt][nt][r] + gelu_f(u);
                hx[((size_t)o << 16) + y] = hn;
                if (do_fy) {
                    int sl = (nt * 16 + l15) ^ ((o & 7) << 3);
                    hlsh[wv][o * 64 + sl] = bf16_rne(hn);
                }
            }
        }
    if (do_fy)
        dft_y_mfma(&hlsh[wv][0], red, wfyh, wfyl, gy, b, x, wv, lk, l15, tid);
}

// ---------------------------------------------------------------------------
// MFMA decoder (round-16 version — best known: 130 us, VGPR 52, occ 39%):
// MT=2 grid 4096, single-bf16 activations, z1 single bf16, weights hi/lo,
// blk loop unrolled x2 only (full unroll caused VGPR 92 + occupancy loss).
// ---------------------------------------------------------------------------
__global__ void __launch_bounds__(256) k_decode(const float* __restrict__ h,
        const short* __restrict__ wb1h, const short* __restrict__ wb1l,
        const float* __restrict__ b1,
        const short* __restrict__ wb2h, const short* __restrict__ wb2l,
        const float* __restrict__ b2,
        const float* __restrict__ w3, const float* __restrict__ b3,
        float* __restrict__ out) {
    __shared__ short z1s[4][32][32];        // per-wave, swizzled, 8 KB
    int tid = threadIdx.x;
    int wv = tid >> 6, l = tid & 63;
    int l15 = l & 15, lk = l >> 4;
    int b = blockIdx.x >> 9;
    int pos0 = (blockIdx.x & 511) * 128;

    bf16x8 ah[2];
    const float* hb = h + (((size_t)b * 32) << 16) + pos0;
#pragma unroll
    for (int mt = 0; mt < 2; ++mt) {
        int p = wv * 32 + mt * 16 + l15;
#pragma unroll
        for (int j = 0; j < 8; ++j)
            ah[mt][j] = bf16_rne(hb[((size_t)(lk * 8 + j) << 16) + p]);
    }

    size_t gbase = (size_t)blockIdx.x * 128 + wv * 32;
    for (int d = 0; d < 3; ++d) {
        bf16x8 w1h[2], w1l[2];
        float bias1[2];
#pragma unroll
        for (int nb = 0; nb < 2; ++nb) {
            int base = ((d * 2 + nb) * 16 + l15) * 32 + lk * 8;
            w1h[nb] = *(const bf16x8*)(wb1h + base);
            w1l[nb] = *(const bf16x8*)(wb1l + base);
            bias1[nb] = b1[d * 32 + nb * 16 + l15];
        }
#pragma unroll
        for (int mt = 0; mt < 2; ++mt) {
#pragma unroll
            for (int nb = 0; nb < 2; ++nb) {
                f32x4 acc = {0.f, 0.f, 0.f, 0.f};
                acc = __builtin_amdgcn_mfma_f32_16x16x32_bf16(ah[mt], w1l[nb], acc, 0, 0, 0);
                acc = __builtin_amdgcn_mfma_f32_16x16x32_bf16(ah[mt], w1h[nb], acc, 0, 0, 0);
                int c = nb * 16 + l15;
#pragma unroll
                for (int r = 0; r < 4; ++r) {
                    float z = gelu_f(acc[r] + bias1[nb]);
                    int rw = mt * 16 + lk * 4 + r;
                    z1s[wv][rw][(((c >> 2) ^ (rw & 7)) << 2) | (c & 3)] = bf16_rne(z);
                }
            }
        }
        bf16x8 zah[2];
#pragma unroll
        for (int mt = 0; mt < 2; ++mt) {
            int rwr = mt * 16 + l15;
            int sl0 = (2 * lk) ^ (rwr & 7);
            int sl1 = (2 * lk + 1) ^ (rwr & 7);
            s16x4 q0 = *(const s16x4*)&z1s[wv][rwr][sl0 << 2];
            s16x4 q1 = *(const s16x4*)&z1s[wv][rwr][sl1 << 2];
#pragma unroll
            for (int j = 0; j < 4; ++j) {
                zah[mt][j]     = q0[j];
                zah[mt][4 + j] = q1[j];
            }
        }
        float p3[2][4];
#pragma unroll
        for (int mt = 0; mt < 2; ++mt)
#pragma unroll
            for (int r = 0; r < 4; ++r) p3[mt][r] = 0.f;
#pragma unroll 2
        for (int blk = 0; blk < 8; ++blk) {
            int base = ((d * 8 + blk) * 16 + l15) * 32 + lk * 8;
            bf16x8 bh  = *(const bf16x8*)(wb2h + base);
            bf16x8 bl2 = *(const bf16x8*)(wb2l + base);
            float bias2 = b2[d * 128 + blk * 16 + l15];
            float w3v   = w3[d * 128 + blk * 16 + l15];
#pragma unroll
            for (int mt = 0; mt < 2; ++mt) {
                f32x4 acc = {0.f, 0.f, 0.f, 0.f};
                acc = __builtin_amdgcn_mfma_f32_16x16x32_bf16(zah[mt], bl2, acc, 0, 0, 0);
                acc = __builtin_amdgcn_mfma_f32_16x16x32_bf16(zah[mt], bh, acc, 0, 0, 0);
#pragma unroll
                for (int r = 0; r < 4; ++r)
                    p3[mt][r] = fmaf(gelu_f(acc[r] + bias2), w3v, p3[mt][r]);
            }
        }
        float b3d = b3[d];
#pragma unroll
        for (int mt = 0; mt < 2; ++mt) {
#pragma unroll
            for (int r = 0; r < 4; ++r) {
                float v = p3[mt][r];
                v += __shfl_xor(v, 1, 64);
                v += __shfl_xor(v, 2, 64);
                v += __shfl_xor(v, 4, 64);
                v += __shfl_xor(v, 8, 64);
                if (l15 == r)
                    out[(gbase + mt * 16 + lk * 4 + r) * 3 + d] = v + b3d;
            }
        }
    }
}

// ---------------------------------------------------------------------------
// Workspace (floats). Total = 21,138,432 floats = 84,553,728 B — under
// round-1's proven-safe 84,934,656 B.
// ---------------------------------------------------------------------------
extern "C" void kernel_launch(void* const* d_in, const int* in_sizes, int n_in,
                              void* d_out, int out_size, void* d_ws, size_t ws_size,
                              hipStream_t stream) {
    const float* bc      = (const float*)d_in[0];
    const float* xg      = (const float*)d_in[1];
    const float* yg      = (const float*)d_in[2];
    const float* mlp1_w  = (const float*)d_in[3];
    const float* mlp1_b  = (const float*)d_in[4];
    const float* spec_wr = (const float*)d_in[5];
    const float* spec_wi = (const float*)d_in[6];
    const float* pw_w    = (const float*)d_in[7];
    const float* pw_b    = (const float*)d_in[8];
    const float* dec_w1  = (const float*)d_in[9];
    const float* dec_b1  = (const float*)d_in[10];
    const float* dec_w2  = (const float*)d_in[11];
    const float* dec_b2  = (const float*)d_in[12];
    const float* dec_w3  = (const float*)d_in[13];
    const float* dec_b3  = (const float*)d_in[14];
    float* out = (float*)d_out;

    float* h    = (float*)d_ws;               // 16,777,216 floats
    float* gi   = h + 16777216;               //  2,097,152
    float* gy   = gi + 2097152;               //  2,097,152
    float* Xf   = gy + 2097152;               //    131,072
    short* wb1h = (short*)(Xf + 131072);      //      3,072 shorts
    short* wb1l = wb1h + 3072;                //      3,072
    short* wb2h = wb1l + 3072;                //     12,288
    short* wb2l = wb2h + 12288;               //     12,288
    short* wpwh = wb2l + 12288;               //      4,096
    short* wpwl = wpwh + 4096;                //      4,096
    short* wifh = wpwl + 4096;                //      8,192
    short* wifl = wifh + 8192;                //      8,192
    short* wfyh = wifl + 8192;                //      8,192
    short* wfyl = wfyh + 8192;                //      8,192
    (void)ws_size; (void)n_in; (void)in_sizes; (void)out_size;

    k_prep<<<32, 256, 0, stream>>>(dec_w1, dec_w2, pw_w,
                                   wb1h, wb1l, wb2h, wb2l,
                                   wpwh, wpwl, wifh, wifl, wfyh, wfyl);
    k_lift_fy<<<2048, 256, 0, stream>>>(bc, xg, yg, mlp1_w, mlp1_b, h,
                                        wfyh, wfyl, gy);
    for (int l = 0; l < NL; ++l) {
        k_fwd_x<<<256, 1024, 0, stream>>>(gy, Xf);
        k_spec<<<256, 1024, 0, stream>>>(Xf, spec_wr + (size_t)l * 262144,
                                         spec_wi + (size_t)l * 262144, gi);
        k_update<<<2048, 256, 0, stream>>>(h, gi, wpwh + l * 1024, wpwl + l * 1024,
                                           pw_b + l * 32, wifh, wifl,
                                           wfyh, wfyl, gy, (l < NL - 1) ? 1 : 0);
    }
    k_decode<<<4096, 256, 0, stream>>>(h, wb1h, wb1l, dec_b1, wb2h, wb2l, dec_b2,
                                       dec_w3, dec_b3, out);
}